// Round 13
// baseline (502.423 us; speedup 1.0000x reference)
//
#include <hip/hip_runtime.h>

typedef _Float16 f16;
typedef __attribute__((ext_vector_type(8))) _Float16 f16x8;
typedef __attribute__((ext_vector_type(4))) _Float16 f16x4;
typedef __attribute__((ext_vector_type(4))) float f32x4;

#define BATCH 16
#define NSEQ  2048
#define DDIM  300
#define DPK   328   // padded row length (f16) for row-major Xf/Yf (zeros in [300,328))
#define DPV   304   // padded d-rows for transposed XT/YT (zeros in [300,304))
#define NTP   2056  // padded q-cols for transposed copies (zeros in [2048,2056))
#define XF_ELEMS (BATCH*NSEQ*DPK)
#define XT_ELEMS (BATCH*DPV*NTP)

__device__ __forceinline__ void gl_lds16(const void* g, void* l) {
  __builtin_amdgcn_global_load_lds((const __attribute__((address_space(1))) unsigned int*)g,
                                   (__attribute__((address_space(3))) unsigned int*)l, 16, 0, 0);
}

// ---------------------------------------------------------------------------
// Preprocess: X,Y f32 -> f16 row-major (padded) + f16 transposed (padded)
// ---------------------------------------------------------------------------
__global__ __launch_bounds__(256) void prep_kernel(const float* __restrict__ X,
                                                   const float* __restrict__ Y,
                                                   f16* __restrict__ Xf, f16* __restrict__ Yf,
                                                   f16* __restrict__ XT, f16* __restrict__ YT) {
  __shared__ float tile[32][33];
  int bz   = blockIdx.z;            // 0..31 = tensor*16 + b
  int tsel = bz >> 4, b = bz & 15;
  const float* src = tsel ? Y : X;
  f16* dF = tsel ? Yf : Xf;
  f16* dT = tsel ? YT : XT;
  int d0 = blockIdx.y * 32;
  int q0 = blockIdx.x * 32;
  int tid = threadIdx.x;
  int c = tid & 31, rr = tid >> 5;

  #pragma unroll
  for (int i = 0; i < 4; ++i) {
    int qr = rr + i * 8;
    int q = q0 + qr, d = d0 + c;
    float v = 0.f;
    if (q < NSEQ && d < DDIM) v = src[(size_t)b * NSEQ * DDIM + (size_t)q * DDIM + d];
    tile[c][qr] = v;
    if (q < NSEQ && d < DPK) dF[(size_t)b * NSEQ * DPK + (size_t)q * DPK + d] = (f16)v;
  }
  __syncthreads();
  #pragma unroll
  for (int i = 0; i < 4; ++i) {
    int dr = rr + i * 8;
    int d = d0 + dr, q = q0 + c;
    if (d < DPV && q < NTP) dT[(size_t)b * DPV * NTP + (size_t)d * NTP + q] = (f16)tile[dr][c];
  }
}

// ---------------------------------------------------------------------------
// Flash attention v13 = R9's merged-cluster pipeline with V moved OUT of LDS:
// each wave loads its d-split V^T fragments global->VGPR one tile ahead
// (vr[10], statically indexed), PV consumes registers. Eliminates stageV
// (1520 chunks/tile), 10 of 22 ds_read_b128/wave/tile, and ~half the bank
// conflicts (2.464e7 constant since R3 = 2-way aliasing on fragment reads).
// LDS pipe was the binding resource (~3200 of 4400 cyc/tile): K+V+P reads
// 2100 + stage writes 350 + conflicts 750.
// Iter t: phase1 {PV[t-1](vr,Psh) + QK^T[t](Ksh)} -> issue V[t] reg-loads
// -> stageK(t+1) -> shfl-max/Mx -> B1(lgkm) -> exp/P-write -> B2(lgkm+
// vmcnt(0), drains loads issued ~2000cyc earlier; makes K[t+1] visible to
// all waves). Epilogue PV[63]. lsum: per-lane partials, epilogue reduce.
// LDS 52736 B (K dbuf 41984 + P 10240 + Mx 512). 8 waves = 4 qg x 2 members,
// QBLK=128, KV=32. Grid 512, XCD-swizzled. __launch_bounds__(512,1).
// ---------------------------------------------------------------------------
__global__ __launch_bounds__(512, 1) void attn_kernel(const f16* __restrict__ Xf,
                                                      const f16* __restrict__ Yf,
                                                      const f16* __restrict__ XT,
                                                      const f16* __restrict__ YT,
                                                      float* __restrict__ out) {
  __shared__ __align__(16) f16 Ksh[2][32][DPK];   // 41984 B (656 B rows)
  __shared__ __align__(16) f16 Psh[4][32][40];    // 10240 B per-qg P
  __shared__ float2 Mx[4][2][16];                 //   512 B max/lsum exchange
                                                  // total 52736 B

  int idx = blockIdx.x;
  int swz = (idx & 7) * 64 + (idx >> 3);          // 512 % 8 == 0: bijective XCD chunking
  int qt  = swz & 15;
  int b   = (swz >> 4) & 15;
  int dir = swz >> 8;

  const f16* Qsrc = dir ? Yf : Xf;
  const f16* Ksrc = dir ? Xf : Yf;
  const f16* Vts  = dir ? XT : YT;   // V^T source [DPV][NTP]

  const size_t bq = (size_t)b * NSEQ * DPK;
  const size_t bt = (size_t)b * DPV * NTP;

  int tid = threadIdx.x;
  int lane = tid & 63, wid = tid >> 6;
  int qg = wid >> 1, mem = wid & 1;
  int l15 = lane & 15, g = lane >> 4;
  int qbase = qt * 128 + qg * 32;     // q-group's 32 rows (shared by both members)

  // Q fragments (both members hold qg's 32 q): lane = Q[q=qi*16+l15][ks*32+g*8+j]
  f16x8 qf[2][10];
  #pragma unroll
  for (int qi = 0; qi < 2; ++qi) {
    const f16* qrow = Qsrc + bq + (size_t)(qbase + qi * 16 + l15) * DPK + g * 8;
    #pragma unroll
    for (int ks = 0; ks < 10; ++ks) qf[qi][ks] = *(const f16x8*)(qrow + ks * 32);
  }

  const int dtoff = mem ? 10 : 0;     // PV d-tiles: member0 d 0..159, member1 160..303
  const int ndt   = mem ? 9 : 10;

  f32x4 O[10][2];
  #pragma unroll
  for (int dt = 0; dt < 10; ++dt) {
    O[dt][0] = (f32x4){0.f, 0.f, 0.f, 0.f};
    O[dt][1] = (f32x4){0.f, 0.f, 0.f, 0.f};
  }
  float m0 = -3.0e38f, m1 = -3.0e38f;
  float l0 = 0.f, l1 = 0.f;           // per-LANE partials (reduced in epilogue)

  // V fragment base for this wave: row (dtoff+dt)*16 + l15, col g*8 (+ t*32)
  const f16* gVb = Vts + bt + (size_t)(dtoff * 16 + l15) * NTP + g * 8;
  f16x8 vr[10];                       // V[t] fragments, loaded one tile ahead

  const char* gK0 = (const char*)(Ksrc + bq);

  auto stageK = [&](int tt, int buf) {
    const char* gK = gK0 + (size_t)tt * (32 * DPK * 2);
    char* lK = (char*)&Ksh[buf][0][0];
    #pragma unroll
    for (int i = 0; i < 3; ++i) {          // 1312 chunks of 16 B
      int c = i * 512 + tid;
      if (c < 1312) gl_lds16(gK + c * 16, lK + c * 16);
    }
  };

  stageK(0, 0);                             // K[0] -> buf0
  asm volatile("s_waitcnt vmcnt(0)" ::: "memory");
  __builtin_amdgcn_s_barrier();
  __builtin_amdgcn_sched_barrier(0);

  #pragma unroll 1
  for (int t = 0; t < 64; ++t) {
    int kcur = t & 1;                       // K[t] buffer

    // ---- Phase 1: merged MFMA cluster — PV[t-1] (vr regs + Psh) + QK^T[t]
    f32x4 S0 = (f32x4){0.f,0.f,0.f,0.f}, S1 = (f32x4){0.f,0.f,0.f,0.f};
    __builtin_amdgcn_s_setprio(1);
    if (t > 0) {
      f16x8 pb0 = *(const f16x8*)&Psh[qg][l15][g * 8];
      f16x8 pb1 = *(const f16x8*)&Psh[qg][16 + l15][g * 8];
      #pragma unroll
      for (int dt = 0; dt < 10; ++dt) {
        if (dt < ndt) {
          O[dt][0] = __builtin_amdgcn_mfma_f32_16x16x32_f16(vr[dt], pb0, O[dt][0], 0, 0, 0);
          O[dt][1] = __builtin_amdgcn_mfma_f32_16x16x32_f16(vr[dt], pb1, O[dt][1], 0, 0, 0);
        }
      }
    }
    #pragma unroll
    for (int ks = 0; ks < 10; ++ks) {
      f16x8 a = *(const f16x8*)&Ksh[kcur][mem * 16 + l15][ks * 32 + g * 8];
      S0 = __builtin_amdgcn_mfma_f32_16x16x32_f16(a, qf[0][ks], S0, 0, 0, 0);
      S1 = __builtin_amdgcn_mfma_f32_16x16x32_f16(a, qf[1][ks], S1, 0, 0, 0);
    }
    __builtin_amdgcn_s_setprio(0);
    __builtin_amdgcn_sched_barrier(0);      // keep V loads below the cluster

    // ---- Phase B: issue V[t] fragment loads (consumed in phase1 of t+1)
    {
      const f16* gVt = gVb + (size_t)t * 32;
      #pragma unroll
      for (int dt = 0; dt < 10; ++dt)
        if (dt < ndt) vr[dt] = *(const f16x8*)(gVt + (size_t)(dt * 16) * NTP);
    }
    // ---- Phase C: stage K[t+1] (WAR-safe: buf's readers done before B2[t-1])
    if (t < 63) stageK(t + 1, kcur ^ 1);

    // ---- Phase D: partial max over own 16 kv + Mx write
    float p0 = fmaxf(fmaxf(S0[0], S0[1]), fmaxf(S0[2], S0[3]));
    float p1 = fmaxf(fmaxf(S1[0], S1[1]), fmaxf(S1[2], S1[3]));
    p0 = fmaxf(p0, __shfl_xor(p0, 16, 64)); p0 = fmaxf(p0, __shfl_xor(p0, 32, 64));
    p1 = fmaxf(p1, __shfl_xor(p1, 16, 64)); p1 = fmaxf(p1, __shfl_xor(p1, 32, 64));
    if (g == 0) Mx[qg][mem][l15] = float2{p0, p1};

    // ---- B1: Mx visible; phase1's Psh reads complete (WAR for P-writes below)
    asm volatile("s_waitcnt lgkmcnt(0)" ::: "memory");
    __builtin_amdgcn_s_barrier();
    __builtin_amdgcn_sched_barrier(0);

    // ---- Phase E: combine maxes, defer-max rescale, exp, P-write, partials
    float2 pp = Mx[qg][mem ^ 1][l15];
    float tm0 = fmaxf(p0, pp.x), tm1 = fmaxf(p1, pp.y);

    if (__any(tm0 > m0 + 8.0f)) {          // defer-max (identical in both members)
      float mn = fmaxf(m0, tm0), al = __expf(m0 - mn);
      l0 *= al;
      #pragma unroll
      for (int dt = 0; dt < 10; ++dt) {
        O[dt][0][0] *= al; O[dt][0][1] *= al; O[dt][0][2] *= al; O[dt][0][3] *= al;
      }
      m0 = mn;
    }
    if (__any(tm1 > m1 + 8.0f)) {
      float mn = fmaxf(m1, tm1), al = __expf(m1 - mn);
      l1 *= al;
      #pragma unroll
      for (int dt = 0; dt < 10; ++dt) {
        O[dt][1][0] *= al; O[dt][1][1] *= al; O[dt][1][2] *= al; O[dt][1][3] *= al;
      }
      m1 = mn;
    }

    f16x4 h0, h1;
    #pragma unroll
    for (int r = 0; r < 4; ++r) {
      float e0 = __expf(S0[r] - m0);       // bounded by e^8
      float e1 = __expf(S1[r] - m1);
      h0[r] = (f16)e0; h1[r] = (f16)e1;
      l0 += e0; l1 += e1;                  // per-lane partials; no shfl here
    }
    *(f16x4*)&Psh[qg][l15][mem * 16 + g * 4]      = h0;   // qi=0 rows
    *(f16x4*)&Psh[qg][16 + l15][mem * 16 + g * 4] = h1;   // qi=1 rows

    // ---- B2: P[t] visible; K[t+1] staged by ALL waves (vmcnt(0) drains loads
    //      issued ~2000 cyc earlier; V[t] regs incidentally covered)
    asm volatile("s_waitcnt lgkmcnt(0) vmcnt(0)" ::: "memory");
    __builtin_amdgcn_s_barrier();
    __builtin_amdgcn_sched_barrier(0);
  }

  // ---- Epilogue PV[63] (trailing tile; vr holds V[63], Psh holds P[63])
  {
    f16x8 pb0 = *(const f16x8*)&Psh[qg][l15][g * 8];
    f16x8 pb1 = *(const f16x8*)&Psh[qg][16 + l15][g * 8];
    __builtin_amdgcn_s_setprio(1);
    #pragma unroll
    for (int dt = 0; dt < 10; ++dt) {
      if (dt < ndt) {
        O[dt][0] = __builtin_amdgcn_mfma_f32_16x16x32_f16(vr[dt], pb0, O[dt][0], 0, 0, 0);
        O[dt][1] = __builtin_amdgcn_mfma_f32_16x16x32_f16(vr[dt], pb1, O[dt][1], 0, 0, 0);
      }
    }
    __builtin_amdgcn_s_setprio(0);
  }

  // ---- reduce per-lane partials across g, exchange with partner member
  l0 += __shfl_xor(l0, 16, 64); l0 += __shfl_xor(l0, 32, 64);
  l1 += __shfl_xor(l1, 16, 64); l1 += __shfl_xor(l1, 32, 64);
  if (g == 0) Mx[qg][mem][l15] = float2{l0, l1};
  asm volatile("s_waitcnt lgkmcnt(0)" ::: "memory");
  __builtin_amdgcn_s_barrier();
  __builtin_amdgcn_sched_barrier(0);
  float2 pl = Mx[qg][mem ^ 1][l15];
  float r0 = 1.0f / (l0 + pl.x);
  float r1 = 1.0f / (l1 + pl.y);

  #pragma unroll
  for (int qi = 0; qi < 2; ++qi) {
    float rinv = qi ? r1 : r0;
    int q = qbase + qi * 16 + l15;
    const f16* mrow = Qsrc + bq + (size_t)q * DPK;
    size_t orow = (size_t)b * (4096 * 300) + (size_t)(dir * 2048 + q) * 300;
    #pragma unroll
    for (int dt = 0; dt < 10; ++dt) {
      if (dt < ndt) {
        int d = (dtoff + dt) * 16 + g * 4;
        if (d < 300) {
          f16x4 mu = *(const f16x4*)(mrow + d);
          f32x4 o;
          o[0] = O[dt][qi][0] * rinv * (float)mu[0];
          o[1] = O[dt][qi][1] * rinv * (float)mu[1];
          o[2] = O[dt][qi][2] * rinv * (float)mu[2];
          o[3] = O[dt][qi][3] * rinv * (float)mu[3];
          *(f32x4*)&out[orow + d] = o;
        }
      }
    }
  }
}

extern "C" void kernel_launch(void* const* d_in, const int* in_sizes, int n_in,
                              void* d_out, int out_size, void* d_ws, size_t ws_size,
                              hipStream_t stream) {
  const float* X = (const float*)d_in[0];
  const float* Y = (const float*)d_in[1];
  float* out = (float*)d_out;

  size_t need = (size_t)(2 * XF_ELEMS + 2 * XT_ELEMS) * sizeof(f16);  // ~83 MB
  if (ws_size < need) return;

  f16* Xf = (f16*)d_ws;
  f16* Yf = Xf + XF_ELEMS;
  f16* XT = Yf + XF_ELEMS;
  f16* YT = XT + XT_ELEMS;

  prep_kernel<<<dim3(65, 11, 32), 256, 0, stream>>>(X, Y, Xf, Yf, XT, YT);
  attn_kernel<<<dim3(512), 512, 0, stream>>>(Xf, Yf, XT, YT, out);
}

// Round 14
// 255.798 us; speedup vs baseline: 1.9641x; 1.9641x over previous
//
#include <hip/hip_runtime.h>

typedef _Float16 f16;
typedef __attribute__((ext_vector_type(8))) _Float16 f16x8;
typedef __attribute__((ext_vector_type(4))) _Float16 f16x4;
typedef __attribute__((ext_vector_type(4))) float f32x4;

#define BATCH 16
#define NSEQ  2048
#define DDIM  300
#define DPK   328   // padded row length (f16) for row-major Xf/Yf (zeros in [300,328))
#define DPV   304   // padded d-rows for transposed XT/YT (zeros in [300,304))
#define NTP   2056  // padded q-cols for transposed copies (zeros in [2048,2056))
#define XF_ELEMS (BATCH*NSEQ*DPK)
#define XT_ELEMS (BATCH*DPV*NTP)

__device__ __forceinline__ void gl_lds16(const void* g, void* l) {
  __builtin_amdgcn_global_load_lds((const __attribute__((address_space(1))) unsigned int*)g,
                                   (__attribute__((address_space(3))) unsigned int*)l, 16, 0, 0);
}

// ---------------------------------------------------------------------------
// Preprocess: X,Y f32 -> f16 row-major (padded) + f16 transposed (padded)
// ---------------------------------------------------------------------------
__global__ __launch_bounds__(256) void prep_kernel(const float* __restrict__ X,
                                                   const float* __restrict__ Y,
                                                   f16* __restrict__ Xf, f16* __restrict__ Yf,
                                                   f16* __restrict__ XT, f16* __restrict__ YT) {
  __shared__ float tile[32][33];
  int bz   = blockIdx.z;            // 0..31 = tensor*16 + b
  int tsel = bz >> 4, b = bz & 15;
  const float* src = tsel ? Y : X;
  f16* dF = tsel ? Yf : Xf;
  f16* dT = tsel ? YT : XT;
  int d0 = blockIdx.y * 32;
  int q0 = blockIdx.x * 32;
  int tid = threadIdx.x;
  int c = tid & 31, rr = tid >> 5;

  #pragma unroll
  for (int i = 0; i < 4; ++i) {
    int qr = rr + i * 8;
    int q = q0 + qr, d = d0 + c;
    float v = 0.f;
    if (q < NSEQ && d < DDIM) v = src[(size_t)b * NSEQ * DDIM + (size_t)q * DDIM + d];
    tile[c][qr] = v;
    if (q < NSEQ && d < DPK) dF[(size_t)b * NSEQ * DPK + (size_t)q * DPK + d] = (f16)v;
  }
  __syncthreads();
  #pragma unroll
  for (int i = 0; i < 4; ++i) {
    int dr = rr + i * 8;
    int d = d0 + dr, q = q0 + c;
    if (d < DPV && q < NTP) dT[(size_t)b * DPV * NTP + (size_t)d * NTP + q] = (f16)tile[dr][c];
  }
}

// ---------------------------------------------------------------------------
// Flash attention v14 = R9's schedule at KVBLK=64: one serial softmax chain
// + 2 barriers per 64 kv (R9 paid 2 chains + 4 barriers). R13 lesson: no
// register headroom (128-VGPR cliff) — S grows only 8 regs here (~125 nat).
// LDS 146.7 KB (1 block/CU): Ksh dbuf 64-row 84K; VTsh SINGLE [304][72]
// 43.8K (144 B rows, conflict-free; staged with linear-dest 16 B/row
// overread — ws reordered XT,YT,Xf,Yf so overread stays in-bounds);
// Psh [4][32][72] 18.4K; Mx 512 B.
// Iter t (32): phase1 {PV[t-1]: 40 MFMA (VTsh,Psh) + QK^T[t]: 40 MFMA} ->
// stageK(t+1, dbuf) -> shfl-max/Mx -> B1(lgkm; phase1 V/P reads done) ->
// stageV(t) into single buffer (race-free) -> exp x16 / P-write / per-lane
// lsum -> B2(lgkm+vmcnt(0): P[t],K[t+1],V[t] visible). Epilogue PV[31].
// 8 waves = 4 qg x 2 members, QBLK=128, kv-split QK^T + d-split PV.
// Grid 512, XCD-swizzled. __launch_bounds__(512,1) (allocator untouched).
// ---------------------------------------------------------------------------
__global__ __launch_bounds__(512, 1) void attn_kernel(const f16* __restrict__ Xf,
                                                      const f16* __restrict__ Yf,
                                                      const f16* __restrict__ XT,
                                                      const f16* __restrict__ YT,
                                                      float* __restrict__ out) {
  __shared__ __align__(16) f16 Ksh[2][64][DPK];   // 83968 B (656 B rows)
  __shared__ __align__(16) f16 VTsh[DPV][72];     // 43776 B (144 B rows, single)
  __shared__ __align__(16) f16 Psh[4][32][72];    // 18432 B per-qg P (144 B rows)
  __shared__ float2 Mx[4][2][16];                 //   512 B max/lsum exchange
                                                  // total 146688 B

  int idx = blockIdx.x;
  int swz = (idx & 7) * 64 + (idx >> 3);          // 512 % 8 == 0: bijective XCD chunking
  int qt  = swz & 15;
  int b   = (swz >> 4) & 15;
  int dir = swz >> 8;

  const f16* Qsrc = dir ? Yf : Xf;
  const f16* Ksrc = dir ? Xf : Yf;
  const f16* Vts  = dir ? XT : YT;   // V^T source [DPV][NTP]

  const size_t bq = (size_t)b * NSEQ * DPK;
  const size_t bt = (size_t)b * DPV * NTP;

  int tid = threadIdx.x;
  int lane = tid & 63, wid = tid >> 6;
  int qg = wid >> 1, mem = wid & 1;
  int l15 = lane & 15, g = lane >> 4;
  int qbase = qt * 128 + qg * 32;     // q-group's 32 rows (shared by both members)

  // Q fragments (both members hold qg's 32 q): lane = Q[q=qi*16+l15][ks*32+g*8+j]
  f16x8 qf[2][10];
  #pragma unroll
  for (int qi = 0; qi < 2; ++qi) {
    const f16* qrow = Qsrc + bq + (size_t)(qbase + qi * 16 + l15) * DPK + g * 8;
    #pragma unroll
    for (int ks = 0; ks < 10; ++ks) qf[qi][ks] = *(const f16x8*)(qrow + ks * 32);
  }

  const int dtoff = mem ? 10 : 0;     // PV d-tiles: member0 d 0..159, member1 160..303
  const int ndt   = mem ? 9 : 10;

  f32x4 O[10][2];
  #pragma unroll
  for (int dt = 0; dt < 10; ++dt) {
    O[dt][0] = (f32x4){0.f, 0.f, 0.f, 0.f};
    O[dt][1] = (f32x4){0.f, 0.f, 0.f, 0.f};
  }
  float m0 = -3.0e38f, m1 = -3.0e38f;
  float l0 = 0.f, l1 = 0.f;           // per-LANE partials (reduced in epilogue)

  const char* gK0 = (const char*)(Ksrc + bq);
  const char* gV0 = (const char*)(Vts + bt);

  auto stageK = [&](int tt, int buf) {           // 64 rows x 656 B = 2624 chunks
    const char* gK = gK0 + (size_t)tt * (64 * DPK * 2);
    char* lK = (char*)&Ksh[buf][0][0];
    #pragma unroll
    for (int i = 0; i < 6; ++i) {
      int c = i * 512 + tid;
      if (c < 2624) gl_lds16(gK + c * 16, lK + c * 16);
    }
  };
  auto stageV = [&](int tt) {                    // 304 rows x 9 slots (128 B data +
    const char* gV = gV0 + (size_t)tt * 128;     //  16 B benign overread) = 2736 chunks
    char* lV = (char*)&VTsh[0][0];
    #pragma unroll
    for (int i = 0; i < 6; ++i) {
      int c = i * 512 + tid;
      if (c < 2736) {
        int row = (int)((unsigned)c / 9u), slot = c - row * 9;
        gl_lds16(gV + (size_t)row * (NTP * 2) + slot * 16, lV + c * 16);
      }
    }
  };

  stageK(0, 0);                             // K[0] -> buf0
  asm volatile("s_waitcnt vmcnt(0)" ::: "memory");
  __builtin_amdgcn_s_barrier();
  __builtin_amdgcn_sched_barrier(0);

  #pragma unroll 1
  for (int t = 0; t < 32; ++t) {
    int kcur = t & 1;                       // K[t] buffer

    // ---- Phase 1: merged MFMA cluster — PV[t-1] (VTsh+Psh) + QK^T[t] (Ksh)
    f32x4 S[2][2];                          // S[kvt][qi]
    S[0][0] = (f32x4){0.f,0.f,0.f,0.f}; S[0][1] = (f32x4){0.f,0.f,0.f,0.f};
    S[1][0] = (f32x4){0.f,0.f,0.f,0.f}; S[1][1] = (f32x4){0.f,0.f,0.f,0.f};
    __builtin_amdgcn_s_setprio(1);
    if (t > 0) {
      #pragma unroll
      for (int ks = 0; ks < 2; ++ks) {
        f16x8 pb0 = *(const f16x8*)&Psh[qg][l15][ks * 32 + g * 8];
        f16x8 pb1 = *(const f16x8*)&Psh[qg][16 + l15][ks * 32 + g * 8];
        #pragma unroll
        for (int dt = 0; dt < 10; ++dt) {
          if (dt < ndt) {
            f16x8 vf = *(const f16x8*)&VTsh[(dtoff + dt) * 16 + l15][ks * 32 + g * 8];
            O[dt][0] = __builtin_amdgcn_mfma_f32_16x16x32_f16(vf, pb0, O[dt][0], 0, 0, 0);
            O[dt][1] = __builtin_amdgcn_mfma_f32_16x16x32_f16(vf, pb1, O[dt][1], 0, 0, 0);
          }
        }
      }
    }
    #pragma unroll
    for (int ks = 0; ks < 10; ++ks) {
      f16x8 a0 = *(const f16x8*)&Ksh[kcur][mem * 32 + l15][ks * 32 + g * 8];
      f16x8 a1 = *(const f16x8*)&Ksh[kcur][mem * 32 + 16 + l15][ks * 32 + g * 8];
      S[0][0] = __builtin_amdgcn_mfma_f32_16x16x32_f16(a0, qf[0][ks], S[0][0], 0, 0, 0);
      S[0][1] = __builtin_amdgcn_mfma_f32_16x16x32_f16(a0, qf[1][ks], S[0][1], 0, 0, 0);
      S[1][0] = __builtin_amdgcn_mfma_f32_16x16x32_f16(a1, qf[0][ks], S[1][0], 0, 0, 0);
      S[1][1] = __builtin_amdgcn_mfma_f32_16x16x32_f16(a1, qf[1][ks], S[1][1], 0, 0, 0);
    }
    __builtin_amdgcn_s_setprio(0);

    // ---- stage K[t+1] (dbuf; WAR-safe: buf readers finished before B2[t-1])
    if (t < 31) stageK(t + 1, kcur ^ 1);

    // ---- partial max over own 32 kv (per q-col = l15, per qi)
    float p0 = fmaxf(fmaxf(fmaxf(S[0][0][0], S[0][0][1]), fmaxf(S[0][0][2], S[0][0][3])),
                     fmaxf(fmaxf(S[1][0][0], S[1][0][1]), fmaxf(S[1][0][2], S[1][0][3])));
    float p1 = fmaxf(fmaxf(fmaxf(S[0][1][0], S[0][1][1]), fmaxf(S[0][1][2], S[0][1][3])),
                     fmaxf(fmaxf(S[1][1][0], S[1][1][1]), fmaxf(S[1][1][2], S[1][1][3])));
    p0 = fmaxf(p0, __shfl_xor(p0, 16, 64)); p0 = fmaxf(p0, __shfl_xor(p0, 32, 64));
    p1 = fmaxf(p1, __shfl_xor(p1, 16, 64)); p1 = fmaxf(p1, __shfl_xor(p1, 32, 64));
    if (g == 0) Mx[qg][mem][l15] = float2{p0, p1};

    // ---- B1: Mx visible; all phase-1 reads of VTsh/Psh complete
    asm volatile("s_waitcnt lgkmcnt(0)" ::: "memory");
    __builtin_amdgcn_s_barrier();
    __builtin_amdgcn_sched_barrier(0);

    // ---- stage V[t] into the single buffer (race-free after B1);
    //      drained at B2, consumed in phase1 of t+1.
    stageV(t);

    // ---- combine maxes, defer-max rescale, exp, P-write, per-lane partials
    float2 pp = Mx[qg][mem ^ 1][l15];
    float tm0 = fmaxf(p0, pp.x), tm1 = fmaxf(p1, pp.y);

    if (__any(tm0 > m0 + 8.0f)) {          // defer-max (identical in both members)
      float mn = fmaxf(m0, tm0), al = __expf(m0 - mn);
      l0 *= al;
      #pragma unroll
      for (int dt = 0; dt < 10; ++dt) {
        O[dt][0][0] *= al; O[dt][0][1] *= al; O[dt][0][2] *= al; O[dt][0][3] *= al;
      }
      m0 = mn;
    }
    if (__any(tm1 > m1 + 8.0f)) {
      float mn = fmaxf(m1, tm1), al = __expf(m1 - mn);
      l1 *= al;
      #pragma unroll
      for (int dt = 0; dt < 10; ++dt) {
        O[dt][1][0] *= al; O[dt][1][1] *= al; O[dt][1][2] *= al; O[dt][1][3] *= al;
      }
      m1 = mn;
    }

    #pragma unroll
    for (int kvt = 0; kvt < 2; ++kvt) {
      f16x4 h0, h1;
      #pragma unroll
      for (int r = 0; r < 4; ++r) {
        float e0 = __expf(S[kvt][0][r] - m0);   // bounded by e^8
        float e1 = __expf(S[kvt][1][r] - m1);
        h0[r] = (f16)e0; h1[r] = (f16)e1;
        l0 += e0; l1 += e1;                     // per-lane partials; no shfl
      }
      *(f16x4*)&Psh[qg][l15][mem * 32 + kvt * 16 + g * 4]      = h0;  // qi=0
      *(f16x4*)&Psh[qg][16 + l15][mem * 32 + kvt * 16 + g * 4] = h1;  // qi=1
    }

    // ---- B2: P[t] visible; K[t+1] (issued ~2000 cyc ago) + V[t] drained
    asm volatile("s_waitcnt lgkmcnt(0) vmcnt(0)" ::: "memory");
    __builtin_amdgcn_s_barrier();
    __builtin_amdgcn_sched_barrier(0);
  }

  // ---- Epilogue PV[31] (trailing tile of the pipeline)
  {
    __builtin_amdgcn_s_setprio(1);
    #pragma unroll
    for (int ks = 0; ks < 2; ++ks) {
      f16x8 pb0 = *(const f16x8*)&Psh[qg][l15][ks * 32 + g * 8];
      f16x8 pb1 = *(const f16x8*)&Psh[qg][16 + l15][ks * 32 + g * 8];
      #pragma unroll
      for (int dt = 0; dt < 10; ++dt) {
        if (dt < ndt) {
          f16x8 vf = *(const f16x8*)&VTsh[(dtoff + dt) * 16 + l15][ks * 32 + g * 8];
          O[dt][0] = __builtin_amdgcn_mfma_f32_16x16x32_f16(vf, pb0, O[dt][0], 0, 0, 0);
          O[dt][1] = __builtin_amdgcn_mfma_f32_16x16x32_f16(vf, pb1, O[dt][1], 0, 0, 0);
        }
      }
    }
    __builtin_amdgcn_s_setprio(0);
  }

  // ---- reduce per-lane partials across g, exchange with partner member
  l0 += __shfl_xor(l0, 16, 64); l0 += __shfl_xor(l0, 32, 64);
  l1 += __shfl_xor(l1, 16, 64); l1 += __shfl_xor(l1, 32, 64);
  if (g == 0) Mx[qg][mem][l15] = float2{l0, l1};
  asm volatile("s_waitcnt lgkmcnt(0)" ::: "memory");
  __builtin_amdgcn_s_barrier();
  __builtin_amdgcn_sched_barrier(0);
  float2 pl = Mx[qg][mem ^ 1][l15];
  float r0 = 1.0f / (l0 + pl.x);
  float r1 = 1.0f / (l1 + pl.y);

  #pragma unroll
  for (int qi = 0; qi < 2; ++qi) {
    float rinv = qi ? r1 : r0;
    int q = qbase + qi * 16 + l15;
    const f16* mrow = Qsrc + bq + (size_t)q * DPK;
    size_t orow = (size_t)b * (4096 * 300) + (size_t)(dir * 2048 + q) * 300;
    #pragma unroll
    for (int dt = 0; dt < 10; ++dt) {
      if (dt < ndt) {
        int d = (dtoff + dt) * 16 + g * 4;
        if (d < 300) {
          f16x4 mu = *(const f16x4*)(mrow + d);
          f32x4 o;
          o[0] = O[dt][qi][0] * rinv * (float)mu[0];
          o[1] = O[dt][qi][1] * rinv * (float)mu[1];
          o[2] = O[dt][qi][2] * rinv * (float)mu[2];
          o[3] = O[dt][qi][3] * rinv * (float)mu[3];
          *(f32x4*)&out[orow + d] = o;
        }
      }
    }
  }
}

extern "C" void kernel_launch(void* const* d_in, const int* in_sizes, int n_in,
                              void* d_out, int out_size, void* d_ws, size_t ws_size,
                              hipStream_t stream) {
  const float* X = (const float*)d_in[0];
  const float* Y = (const float*)d_in[1];
  float* out = (float*)d_out;

  size_t need = (size_t)(2 * XF_ELEMS + 2 * XT_ELEMS) * sizeof(f16);  // ~83 MB
  if (ws_size < need) return;

  // Layout: XT, YT first, Xf, Yf last — stageV's 16 B/row overread on the
  // transposed arrays lands in the following array, never past d_ws.
  f16* XT = (f16*)d_ws;
  f16* YT = XT + XT_ELEMS;
  f16* Xf = YT + XT_ELEMS;
  f16* Yf = Xf + XF_ELEMS;

  prep_kernel<<<dim3(65, 11, 32), 256, 0, stream>>>(X, Y, Xf, Yf, XT, YT);
  attn_kernel<<<dim3(512), 512, 0, stream>>>(Xf, Yf, XT, YT, out);
}

// Round 15
// 253.038 us; speedup vs baseline: 1.9856x; 1.0109x over previous
//
#include <hip/hip_runtime.h>

typedef _Float16 f16;
typedef __attribute__((ext_vector_type(8))) _Float16 f16x8;
typedef __attribute__((ext_vector_type(4))) _Float16 f16x4;
typedef __attribute__((ext_vector_type(4))) float f32x4;

#define BATCH 16
#define NSEQ  2048
#define DDIM  300
#define DPK   328   // padded row length (f16) for row-major Xf/Yf (zeros in [300,328))
#define DPV   304   // padded d-rows for transposed XT/YT (zeros in [300,304))
#define NTP   2056  // padded q-cols for transposed copies (zeros in [2048,2056))
#define XF_ELEMS (BATCH*NSEQ*DPK)
#define XT_ELEMS (BATCH*DPV*NTP)

__device__ __forceinline__ void gl_lds16(const void* g, void* l) {
  __builtin_amdgcn_global_load_lds((const __attribute__((address_space(1))) unsigned int*)g,
                                   (__attribute__((address_space(3))) unsigned int*)l, 16, 0, 0);
}

// ---------------------------------------------------------------------------
// Preprocess: X,Y f32 -> f16 row-major (padded) + f16 transposed (padded)
// ---------------------------------------------------------------------------
__global__ __launch_bounds__(256) void prep_kernel(const float* __restrict__ X,
                                                   const float* __restrict__ Y,
                                                   f16* __restrict__ Xf, f16* __restrict__ Yf,
                                                   f16* __restrict__ XT, f16* __restrict__ YT) {
  __shared__ float tile[32][33];
  int bz   = blockIdx.z;            // 0..31 = tensor*16 + b
  int tsel = bz >> 4, b = bz & 15;
  const float* src = tsel ? Y : X;
  f16* dF = tsel ? Yf : Xf;
  f16* dT = tsel ? YT : XT;
  int d0 = blockIdx.y * 32;
  int q0 = blockIdx.x * 32;
  int tid = threadIdx.x;
  int c = tid & 31, rr = tid >> 5;

  #pragma unroll
  for (int i = 0; i < 4; ++i) {
    int qr = rr + i * 8;
    int q = q0 + qr, d = d0 + c;
    float v = 0.f;
    if (q < NSEQ && d < DDIM) v = src[(size_t)b * NSEQ * DDIM + (size_t)q * DDIM + d];
    tile[c][qr] = v;
    if (q < NSEQ && d < DPK) dF[(size_t)b * NSEQ * DPK + (size_t)q * DPK + d] = (f16)v;
  }
  __syncthreads();
  #pragma unroll
  for (int i = 0; i < 4; ++i) {
    int dr = rr + i * 8;
    int d = d0 + dr, q = q0 + c;
    if (d < DPV && q < NTP) dT[(size_t)b * DPV * NTP + (size_t)d * NTP + q] = (f16)tile[dr][c];
  }
}

// ---------------------------------------------------------------------------
// Flash attention v15 = R14 (KVBLK=64, 2-barrier pipeline, 239 us) with
// register-neutral overlap polish:
//  * phase1 interleaved at half-cluster grain: PV(ks=0) -> QK(ks 0..4) ->
//    PV(ks=1) -> QK(ks 5..9). Each 5-deep dependent S-chain segment now has
//    20 independent PV MFMAs for latency hiding; pb stays 8 regs live.
//  * max trees nested in triples -> v_max3_f32 (7 -> 4 instrs per tree).
// Everything else identical to R14: 8 waves = 4 qg x 2 members, QBLK=128,
// kv-split QK^T + d-split PV, K dbuf / V single (staged after B1), LDS
// 146.7 KB, grid 512 XCD-swizzled, __launch_bounds__(512,1) (VGPR 120,
// 128-cliff respected — watch WRITE_SIZE for spill).
// ---------------------------------------------------------------------------
__global__ __launch_bounds__(512, 1) void attn_kernel(const f16* __restrict__ Xf,
                                                      const f16* __restrict__ Yf,
                                                      const f16* __restrict__ XT,
                                                      const f16* __restrict__ YT,
                                                      float* __restrict__ out) {
  __shared__ __align__(16) f16 Ksh[2][64][DPK];   // 83968 B (656 B rows)
  __shared__ __align__(16) f16 VTsh[DPV][72];     // 43776 B (144 B rows, single)
  __shared__ __align__(16) f16 Psh[4][32][72];    // 18432 B per-qg P (144 B rows)
  __shared__ float2 Mx[4][2][16];                 //   512 B max/lsum exchange
                                                  // total 146688 B

  int idx = blockIdx.x;
  int swz = (idx & 7) * 64 + (idx >> 3);          // 512 % 8 == 0: bijective XCD chunking
  int qt  = swz & 15;
  int b   = (swz >> 4) & 15;
  int dir = swz >> 8;

  const f16* Qsrc = dir ? Yf : Xf;
  const f16* Ksrc = dir ? Xf : Yf;
  const f16* Vts  = dir ? XT : YT;   // V^T source [DPV][NTP]

  const size_t bq = (size_t)b * NSEQ * DPK;
  const size_t bt = (size_t)b * DPV * NTP;

  int tid = threadIdx.x;
  int lane = tid & 63, wid = tid >> 6;
  int qg = wid >> 1, mem = wid & 1;
  int l15 = lane & 15, g = lane >> 4;
  int qbase = qt * 128 + qg * 32;     // q-group's 32 rows (shared by both members)

  // Q fragments (both members hold qg's 32 q): lane = Q[q=qi*16+l15][ks*32+g*8+j]
  f16x8 qf[2][10];
  #pragma unroll
  for (int qi = 0; qi < 2; ++qi) {
    const f16* qrow = Qsrc + bq + (size_t)(qbase + qi * 16 + l15) * DPK + g * 8;
    #pragma unroll
    for (int ks = 0; ks < 10; ++ks) qf[qi][ks] = *(const f16x8*)(qrow + ks * 32);
  }

  const int dtoff = mem ? 10 : 0;     // PV d-tiles: member0 d 0..159, member1 160..303
  const int ndt   = mem ? 9 : 10;

  f32x4 O[10][2];
  #pragma unroll
  for (int dt = 0; dt < 10; ++dt) {
    O[dt][0] = (f32x4){0.f, 0.f, 0.f, 0.f};
    O[dt][1] = (f32x4){0.f, 0.f, 0.f, 0.f};
  }
  float m0 = -3.0e38f, m1 = -3.0e38f;
  float l0 = 0.f, l1 = 0.f;           // per-LANE partials (reduced in epilogue)

  const char* gK0 = (const char*)(Ksrc + bq);
  const char* gV0 = (const char*)(Vts + bt);

  auto stageK = [&](int tt, int buf) {           // 64 rows x 656 B = 2624 chunks
    const char* gK = gK0 + (size_t)tt * (64 * DPK * 2);
    char* lK = (char*)&Ksh[buf][0][0];
    #pragma unroll
    for (int i = 0; i < 6; ++i) {
      int c = i * 512 + tid;
      if (c < 2624) gl_lds16(gK + c * 16, lK + c * 16);
    }
  };
  auto stageV = [&](int tt) {                    // 304 rows x 9 slots (128 B data +
    const char* gV = gV0 + (size_t)tt * 128;     //  16 B benign overread) = 2736 chunks
    char* lV = (char*)&VTsh[0][0];
    #pragma unroll
    for (int i = 0; i < 6; ++i) {
      int c = i * 512 + tid;
      if (c < 2736) {
        int row = (int)((unsigned)c / 9u), slot = c - row * 9;
        gl_lds16(gV + (size_t)row * (NTP * 2) + slot * 16, lV + c * 16);
      }
    }
  };

  stageK(0, 0);                             // K[0] -> buf0
  asm volatile("s_waitcnt vmcnt(0)" ::: "memory");
  __builtin_amdgcn_s_barrier();
  __builtin_amdgcn_sched_barrier(0);

  #pragma unroll 1
  for (int t = 0; t < 32; ++t) {
    int kcur = t & 1;                       // K[t] buffer

    // ---- Phase 1: interleaved MFMA cluster — PV[t-1] / QK^T[t] half-blocks
    f32x4 S[2][2];                          // S[kvt][qi]
    S[0][0] = (f32x4){0.f,0.f,0.f,0.f}; S[0][1] = (f32x4){0.f,0.f,0.f,0.f};
    S[1][0] = (f32x4){0.f,0.f,0.f,0.f}; S[1][1] = (f32x4){0.f,0.f,0.f,0.f};
    __builtin_amdgcn_s_setprio(1);
    if (t > 0) {                            // PV half ks=0 (kv 0..31 of P/V[t-1])
      f16x8 pb0 = *(const f16x8*)&Psh[qg][l15][g * 8];
      f16x8 pb1 = *(const f16x8*)&Psh[qg][16 + l15][g * 8];
      #pragma unroll
      for (int dt = 0; dt < 10; ++dt) {
        if (dt < ndt) {
          f16x8 vf = *(const f16x8*)&VTsh[(dtoff + dt) * 16 + l15][g * 8];
          O[dt][0] = __builtin_amdgcn_mfma_f32_16x16x32_f16(vf, pb0, O[dt][0], 0, 0, 0);
          O[dt][1] = __builtin_amdgcn_mfma_f32_16x16x32_f16(vf, pb1, O[dt][1], 0, 0, 0);
        }
      }
    }
    #pragma unroll
    for (int ks = 0; ks < 5; ++ks) {        // QK first half: S-chain depth 5
      f16x8 a0 = *(const f16x8*)&Ksh[kcur][mem * 32 + l15][ks * 32 + g * 8];
      f16x8 a1 = *(const f16x8*)&Ksh[kcur][mem * 32 + 16 + l15][ks * 32 + g * 8];
      S[0][0] = __builtin_amdgcn_mfma_f32_16x16x32_f16(a0, qf[0][ks], S[0][0], 0, 0, 0);
      S[0][1] = __builtin_amdgcn_mfma_f32_16x16x32_f16(a0, qf[1][ks], S[0][1], 0, 0, 0);
      S[1][0] = __builtin_amdgcn_mfma_f32_16x16x32_f16(a1, qf[0][ks], S[1][0], 0, 0, 0);
      S[1][1] = __builtin_amdgcn_mfma_f32_16x16x32_f16(a1, qf[1][ks], S[1][1], 0, 0, 0);
    }
    if (t > 0) {                            // PV half ks=1 (kv 32..63)
      f16x8 pb0 = *(const f16x8*)&Psh[qg][l15][32 + g * 8];
      f16x8 pb1 = *(const f16x8*)&Psh[qg][16 + l15][32 + g * 8];
      #pragma unroll
      for (int dt = 0; dt < 10; ++dt) {
        if (dt < ndt) {
          f16x8 vf = *(const f16x8*)&VTsh[(dtoff + dt) * 16 + l15][32 + g * 8];
          O[dt][0] = __builtin_amdgcn_mfma_f32_16x16x32_f16(vf, pb0, O[dt][0], 0, 0, 0);
          O[dt][1] = __builtin_amdgcn_mfma_f32_16x16x32_f16(vf, pb1, O[dt][1], 0, 0, 0);
        }
      }
    }
    #pragma unroll
    for (int ks = 5; ks < 10; ++ks) {       // QK second half
      f16x8 a0 = *(const f16x8*)&Ksh[kcur][mem * 32 + l15][ks * 32 + g * 8];
      f16x8 a1 = *(const f16x8*)&Ksh[kcur][mem * 32 + 16 + l15][ks * 32 + g * 8];
      S[0][0] = __builtin_amdgcn_mfma_f32_16x16x32_f16(a0, qf[0][ks], S[0][0], 0, 0, 0);
      S[0][1] = __builtin_amdgcn_mfma_f32_16x16x32_f16(a0, qf[1][ks], S[0][1], 0, 0, 0);
      S[1][0] = __builtin_amdgcn_mfma_f32_16x16x32_f16(a1, qf[0][ks], S[1][0], 0, 0, 0);
      S[1][1] = __builtin_amdgcn_mfma_f32_16x16x32_f16(a1, qf[1][ks], S[1][1], 0, 0, 0);
    }
    __builtin_amdgcn_s_setprio(0);

    // ---- stage K[t+1] (dbuf; WAR-safe: buf readers finished before B2[t-1])
    if (t < 31) stageK(t + 1, kcur ^ 1);

    // ---- partial max over own 32 kv (max3-shaped trees: 4 instrs each)
    float p0 = fmaxf(fmaxf(fmaxf(S[0][0][0], S[0][0][1]), S[0][0][2]),
                     fmaxf(fmaxf(S[0][0][3], S[1][0][0]), S[1][0][1]));
    p0 = fmaxf(fmaxf(p0, S[1][0][2]), S[1][0][3]);
    float p1 = fmaxf(fmaxf(fmaxf(S[0][1][0], S[0][1][1]), S[0][1][2]),
                     fmaxf(fmaxf(S[0][1][3], S[1][1][0]), S[1][1][1]));
    p1 = fmaxf(fmaxf(p1, S[1][1][2]), S[1][1][3]);
    p0 = fmaxf(p0, __shfl_xor(p0, 16, 64)); p0 = fmaxf(p0, __shfl_xor(p0, 32, 64));
    p1 = fmaxf(p1, __shfl_xor(p1, 16, 64)); p1 = fmaxf(p1, __shfl_xor(p1, 32, 64));
    if (g == 0) Mx[qg][mem][l15] = float2{p0, p1};

    // ---- B1: Mx visible; all phase-1 reads of VTsh/Psh complete
    asm volatile("s_waitcnt lgkmcnt(0)" ::: "memory");
    __builtin_amdgcn_s_barrier();
    __builtin_amdgcn_sched_barrier(0);

    // ---- stage V[t] into the single buffer (race-free after B1);
    //      drained at B2, consumed in phase1 of t+1.
    stageV(t);

    // ---- combine maxes, defer-max rescale, exp, P-write, per-lane partials
    float2 pp = Mx[qg][mem ^ 1][l15];
    float tm0 = fmaxf(p0, pp.x), tm1 = fmaxf(p1, pp.y);

    if (__any(tm0 > m0 + 8.0f)) {          // defer-max (identical in both members)
      float mn = fmaxf(m0, tm0), al = __expf(m0 - mn);
      l0 *= al;
      #pragma unroll
      for (int dt = 0; dt < 10; ++dt) {
        O[dt][0][0] *= al; O[dt][0][1] *= al; O[dt][0][2] *= al; O[dt][0][3] *= al;
      }
      m0 = mn;
    }
    if (__any(tm1 > m1 + 8.0f)) {
      float mn = fmaxf(m1, tm1), al = __expf(m1 - mn);
      l1 *= al;
      #pragma unroll
      for (int dt = 0; dt < 10; ++dt) {
        O[dt][1][0] *= al; O[dt][1][1] *= al; O[dt][1][2] *= al; O[dt][1][3] *= al;
      }
      m1 = mn;
    }

    #pragma unroll
    for (int kvt = 0; kvt < 2; ++kvt) {
      f16x4 h0, h1;
      #pragma unroll
      for (int r = 0; r < 4; ++r) {
        float e0 = __expf(S[kvt][0][r] - m0);   // bounded by e^8
        float e1 = __expf(S[kvt][1][r] - m1);
        h0[r] = (f16)e0; h1[r] = (f16)e1;
        l0 += e0; l1 += e1;                     // per-lane partials; no shfl
      }
      *(f16x4*)&Psh[qg][l15][mem * 32 + kvt * 16 + g * 4]      = h0;  // qi=0
      *(f16x4*)&Psh[qg][16 + l15][mem * 32 + kvt * 16 + g * 4] = h1;  // qi=1
    }

    // ---- B2: P[t] visible; K[t+1] (issued ~2000 cyc ago) + V[t] drained
    asm volatile("s_waitcnt lgkmcnt(0) vmcnt(0)" ::: "memory");
    __builtin_amdgcn_s_barrier();
    __builtin_amdgcn_sched_barrier(0);
  }

  // ---- Epilogue PV[31] (trailing tile of the pipeline)
  {
    __builtin_amdgcn_s_setprio(1);
    #pragma unroll
    for (int ks = 0; ks < 2; ++ks) {
      f16x8 pb0 = *(const f16x8*)&Psh[qg][l15][ks * 32 + g * 8];
      f16x8 pb1 = *(const f16x8*)&Psh[qg][16 + l15][ks * 32 + g * 8];
      #pragma unroll
      for (int dt = 0; dt < 10; ++dt) {
        if (dt < ndt) {
          f16x8 vf = *(const f16x8*)&VTsh[(dtoff + dt) * 16 + l15][ks * 32 + g * 8];
          O[dt][0] = __builtin_amdgcn_mfma_f32_16x16x32_f16(vf, pb0, O[dt][0], 0, 0, 0);
          O[dt][1] = __builtin_amdgcn_mfma_f32_16x16x32_f16(vf, pb1, O[dt][1], 0, 0, 0);
        }
      }
    }
    __builtin_amdgcn_s_setprio(0);
  }

  // ---- reduce per-lane partials across g, exchange with partner member
  l0 += __shfl_xor(l0, 16, 64); l0 += __shfl_xor(l0, 32, 64);
  l1 += __shfl_xor(l1, 16, 64); l1 += __shfl_xor(l1, 32, 64);
  if (g == 0) Mx[qg][mem][l15] = float2{l0, l1};
  asm volatile("s_waitcnt lgkmcnt(0)" ::: "memory");
  __builtin_amdgcn_s_barrier();
  __builtin_amdgcn_sched_barrier(0);
  float2 pl = Mx[qg][mem ^ 1][l15];
  float r0 = 1.0f / (l0 + pl.x);
  float r1 = 1.0f / (l1 + pl.y);

  #pragma unroll
  for (int qi = 0; qi < 2; ++qi) {
    float rinv = qi ? r1 : r0;
    int q = qbase + qi * 16 + l15;
    const f16* mrow = Qsrc + bq + (size_t)q * DPK;
    size_t orow = (size_t)b * (4096 * 300) + (size_t)(dir * 2048 + q) * 300;
    #pragma unroll
    for (int dt = 0; dt < 10; ++dt) {
      if (dt < ndt) {
        int d = (dtoff + dt) * 16 + g * 4;
        if (d < 300) {
          f16x4 mu = *(const f16x4*)(mrow + d);
          f32x4 o;
          o[0] = O[dt][qi][0] * rinv * (float)mu[0];
          o[1] = O[dt][qi][1] * rinv * (float)mu[1];
          o[2] = O[dt][qi][2] * rinv * (float)mu[2];
          o[3] = O[dt][qi][3] * rinv * (float)mu[3];
          *(f32x4*)&out[orow + d] = o;
        }
      }
    }
  }
}

extern "C" void kernel_launch(void* const* d_in, const int* in_sizes, int n_in,
                              void* d_out, int out_size, void* d_ws, size_t ws_size,
                              hipStream_t stream) {
  const float* X = (const float*)d_in[0];
  const float* Y = (const float*)d_in[1];
  float* out = (float*)d_out;

  size_t need = (size_t)(2 * XF_ELEMS + 2 * XT_ELEMS) * sizeof(f16);  // ~83 MB
  if (ws_size < need) return;

  // Layout: XT, YT first, Xf, Yf last — stageV's 16 B/row overread on the
  // transposed arrays lands in the following array, never past d_ws.
  f16* XT = (f16*)d_ws;
  f16* YT = XT + XT_ELEMS;
  f16* Xf = YT + XT_ELEMS;
  f16* Yf = Xf + XF_ELEMS;

  prep_kernel<<<dim3(65, 11, 32), 256, 0, stream>>>(X, Y, Xf, Yf, XT, YT);
  attn_kernel<<<dim3(512), 512, 0, stream>>>(Xf, Yf, XT, YT, out);
}

// Round 16
// 244.400 us; speedup vs baseline: 2.0557x; 1.0353x over previous
//
#include <hip/hip_runtime.h>

typedef _Float16 f16;
typedef __attribute__((ext_vector_type(8))) _Float16 f16x8;
typedef __attribute__((ext_vector_type(4))) _Float16 f16x4;
typedef __attribute__((ext_vector_type(4))) float f32x4;
typedef __attribute__((ext_vector_type(16))) float f32x16;

#define BATCH 16
#define NSEQ  2048
#define DDIM  300
#define DPK   328   // padded row length (f16) for row-major Xf/Yf (zeros in [300,328))
#define DPV   304   // padded d-rows for transposed XT/YT (zeros in [300,304))
#define NTP   2056  // padded q-cols for transposed copies (zeros in [2048,2056))
#define XF_ELEMS (BATCH*NSEQ*DPK)
#define XT_ELEMS (BATCH*DPV*NTP)

__device__ __forceinline__ void gl_lds16(const void* g, void* l) {
  __builtin_amdgcn_global_load_lds((const __attribute__((address_space(1))) unsigned int*)g,
                                   (__attribute__((address_space(3))) unsigned int*)l, 16, 0, 0);
}

// ---------------------------------------------------------------------------
// Preprocess: X,Y f32 -> f16 row-major (padded) + f16 transposed (padded)
// ---------------------------------------------------------------------------
__global__ __launch_bounds__(256) void prep_kernel(const float* __restrict__ X,
                                                   const float* __restrict__ Y,
                                                   f16* __restrict__ Xf, f16* __restrict__ Yf,
                                                   f16* __restrict__ XT, f16* __restrict__ YT) {
  __shared__ float tile[32][33];
  int bz   = blockIdx.z;            // 0..31 = tensor*16 + b
  int tsel = bz >> 4, b = bz & 15;
  const float* src = tsel ? Y : X;
  f16* dF = tsel ? Yf : Xf;
  f16* dT = tsel ? YT : XT;
  int d0 = blockIdx.y * 32;
  int q0 = blockIdx.x * 32;
  int tid = threadIdx.x;
  int c = tid & 31, rr = tid >> 5;

  #pragma unroll
  for (int i = 0; i < 4; ++i) {
    int qr = rr + i * 8;
    int q = q0 + qr, d = d0 + c;
    float v = 0.f;
    if (q < NSEQ && d < DDIM) v = src[(size_t)b * NSEQ * DDIM + (size_t)q * DDIM + d];
    tile[c][qr] = v;
    if (q < NSEQ && d < DPK) dF[(size_t)b * NSEQ * DPK + (size_t)q * DPK + d] = (f16)v;
  }
  __syncthreads();
  #pragma unroll
  for (int i = 0; i < 4; ++i) {
    int dr = rr + i * 8;
    int d = d0 + dr, q = q0 + c;
    if (d < DPV && q < NTP) dT[(size_t)b * DPV * NTP + (size_t)d * NTP + q] = (f16)tile[dr][c];
  }
}

// ---------------------------------------------------------------------------
// Flash attention v16 = R15's schedule converted to 32x32x16 MFMA:
// half the MFMA instruction count (QK 40->20, PV ~38->20 per wave/iter),
// same LDS bytes, same register totals (S 16 f32, O 5x16 f32, qf 80 VGPR).
// QK: one 32kv x 32q tile per wave (kv-split by mem); A=K[m=l31][k=hi*8+j],
// B=Q[n=l31][k]; C verified layout: col(q)=lane&31, row(kv)=(reg&3)+
// 8*(reg>>2)+4*hi. Softmax: per-lane q-column, 15-fmax tree + ONE shfl_xor(32)
// (was 4 shfls); single per-lane m/l. PV d-split: member0 d 0..159 (5 tiles),
// member1 d 144..303 (5 tiles, overlap rows computed-not-stored; 300%4==0 so
// stores stay full f32x4 runs). Schedule/barriers/staging identical to R15:
// phase1 {PV[t-1] halves interleaved with QK halves} -> stageK -> max/Mx ->
// B1(lgkm) -> stageV -> exp/P/partials -> B2(lgkm+vmcnt(0)). Epilogue PV[31].
// LDS 147200 B. Grid 512 XCD-swizzled. __launch_bounds__(512,1).
// ---------------------------------------------------------------------------
__global__ __launch_bounds__(512, 1) void attn_kernel(const f16* __restrict__ Xf,
                                                      const f16* __restrict__ Yf,
                                                      const f16* __restrict__ XT,
                                                      const f16* __restrict__ YT,
                                                      float* __restrict__ out) {
  __shared__ __align__(16) f16 Ksh[2][64][DPK];   // 83968 B (656 B rows)
  __shared__ __align__(16) f16 VTsh[DPV][72];     // 43776 B (144 B rows, single)
  __shared__ __align__(16) f16 Psh[4][32][72];    // 18432 B per-qg P (144 B rows)
  __shared__ float MxS[4][2][32];                 //  1024 B max/lsum exchange
                                                  // total 147200 B

  int idx = blockIdx.x;
  int swz = (idx & 7) * 64 + (idx >> 3);          // 512 % 8 == 0: bijective XCD chunking
  int qt  = swz & 15;
  int b   = (swz >> 4) & 15;
  int dir = swz >> 8;

  const f16* Qsrc = dir ? Yf : Xf;
  const f16* Ksrc = dir ? Xf : Yf;
  const f16* Vts  = dir ? XT : YT;   // V^T source [DPV][NTP]

  const size_t bq = (size_t)b * NSEQ * DPK;
  const size_t bt = (size_t)b * DPV * NTP;

  int tid = threadIdx.x;
  int lane = tid & 63, wid = tid >> 6;
  int qg = wid >> 1, mem = wid & 1;
  int l31 = lane & 31, hi = lane >> 5;
  int qbase = qt * 128 + qg * 32;     // q-group's 32 rows (shared by both members)

  // Q fragments (B-operand, 32x32x16): lane = Q[q=qbase+l31][ks*16 + hi*8 + j]
  f16x8 qf[20];
  {
    const f16* qrow = Qsrc + bq + (size_t)(qbase + l31) * DPK + hi * 8;
    #pragma unroll
    for (int ks = 0; ks < 20; ++ks) qf[ks] = *(const f16x8*)(qrow + ks * 16);
  }

  const int dbase = mem ? 144 : 0;    // PV d-tile base (member1 overlaps 144..159)
  const int dlo   = mem ? 160 : 0;    // first d this member STORES

  f32x16 O[5];
  #pragma unroll
  for (int dt = 0; dt < 5; ++dt)
    #pragma unroll
    for (int e = 0; e < 16; ++e) O[dt][e] = 0.f;
  float m = -3.0e38f, l = 0.f;        // per-lane (q = l31) running max / partial sum

  const char* gK0 = (const char*)(Ksrc + bq);
  const char* gV0 = (const char*)(Vts + bt);

  auto stageK = [&](int tt, int buf) {           // 64 rows x 656 B = 2624 chunks
    const char* gK = gK0 + (size_t)tt * (64 * DPK * 2);
    char* lK = (char*)&Ksh[buf][0][0];
    #pragma unroll
    for (int i = 0; i < 6; ++i) {
      int c = i * 512 + tid;
      if (c < 2624) gl_lds16(gK + c * 16, lK + c * 16);
    }
  };
  auto stageV = [&](int tt) {                    // 304 rows x 9 slots (128 B data +
    const char* gV = gV0 + (size_t)tt * 128;     //  16 B benign overread) = 2736 chunks
    char* lV = (char*)&VTsh[0][0];
    #pragma unroll
    for (int i = 0; i < 6; ++i) {
      int c = i * 512 + tid;
      if (c < 2736) {
        int row = (int)((unsigned)c / 9u), slot = c - row * 9;
        gl_lds16(gV + (size_t)row * (NTP * 2) + slot * 16, lV + c * 16);
      }
    }
  };

  stageK(0, 0);                             // K[0] -> buf0
  asm volatile("s_waitcnt vmcnt(0)" ::: "memory");
  __builtin_amdgcn_s_barrier();
  __builtin_amdgcn_sched_barrier(0);

  #pragma unroll 1
  for (int t = 0; t < 32; ++t) {
    int kcur = t & 1;                       // K[t] buffer

    // ---- Phase 1: interleaved MFMA cluster — PV[t-1] / QK^T[t] half-blocks
    f32x16 S;
    #pragma unroll
    for (int e = 0; e < 16; ++e) S[e] = 0.f;
    __builtin_amdgcn_s_setprio(1);
    if (t > 0) {                            // PV half: ks 0,1 (kv 0..31 of tile t-1)
      #pragma unroll
      for (int ks = 0; ks < 2; ++ks) {
        f16x8 pf = *(const f16x8*)&Psh[qg][l31][ks * 16 + hi * 8];
        #pragma unroll
        for (int dt = 0; dt < 5; ++dt) {
          f16x8 vf = *(const f16x8*)&VTsh[dbase + dt * 32 + l31][ks * 16 + hi * 8];
          O[dt] = __builtin_amdgcn_mfma_f32_32x32x16_f16(vf, pf, O[dt], 0, 0, 0);
        }
      }
    }
    #pragma unroll
    for (int ks = 0; ks < 10; ++ks) {       // QK first half
      f16x8 a = *(const f16x8*)&Ksh[kcur][mem * 32 + l31][ks * 16 + hi * 8];
      S = __builtin_amdgcn_mfma_f32_32x32x16_f16(a, qf[ks], S, 0, 0, 0);
    }
    if (t > 0) {                            // PV half: ks 2,3 (kv 32..63)
      #pragma unroll
      for (int ks = 2; ks < 4; ++ks) {
        f16x8 pf = *(const f16x8*)&Psh[qg][l31][ks * 16 + hi * 8];
        #pragma unroll
        for (int dt = 0; dt < 5; ++dt) {
          f16x8 vf = *(const f16x8*)&VTsh[dbase + dt * 32 + l31][ks * 16 + hi * 8];
          O[dt] = __builtin_amdgcn_mfma_f32_32x32x16_f16(vf, pf, O[dt], 0, 0, 0);
        }
      }
    }
    #pragma unroll
    for (int ks = 10; ks < 20; ++ks) {      // QK second half
      f16x8 a = *(const f16x8*)&Ksh[kcur][mem * 32 + l31][ks * 16 + hi * 8];
      S = __builtin_amdgcn_mfma_f32_32x32x16_f16(a, qf[ks], S, 0, 0, 0);
    }
    __builtin_amdgcn_s_setprio(0);

    // ---- stage K[t+1] (dbuf; WAR-safe: buf readers finished before B2[t-1])
    if (t < 31) stageK(t + 1, kcur ^ 1);

    // ---- partial max over own 32 kv for q = l31 (16 in-lane + 1 shfl)
    float p = fmaxf(fmaxf(fmaxf(S[0], S[1]), S[2]),
                    fmaxf(fmaxf(S[3], S[4]), S[5]));
    p = fmaxf(p, fmaxf(fmaxf(S[6], S[7]), fmaxf(S[8], S[9])));
    p = fmaxf(p, fmaxf(fmaxf(S[10], S[11]), fmaxf(S[12], S[13])));
    p = fmaxf(p, fmaxf(S[14], S[15]));
    p = fmaxf(p, __shfl_xor(p, 32, 64));
    if (lane < 32) MxS[qg][mem][l31] = p;

    // ---- B1: Mx visible; all phase-1 reads of VTsh/Psh complete
    asm volatile("s_waitcnt lgkmcnt(0)" ::: "memory");
    __builtin_amdgcn_s_barrier();
    __builtin_amdgcn_sched_barrier(0);

    // ---- stage V[t] into the single buffer (race-free after B1)
    stageV(t);

    // ---- combine maxes, defer-max rescale, exp, P-write, per-lane partials
    float pp = MxS[qg][mem ^ 1][l31];
    float tm = fmaxf(p, pp);

    if (__any(tm > m + 8.0f)) {            // defer-max (identical in both members)
      float mn = fmaxf(m, tm), al = __expf(m - mn);
      l *= al;
      #pragma unroll
      for (int dt = 0; dt < 5; ++dt)
        #pragma unroll
        for (int e = 0; e < 16; ++e) O[dt][e] *= al;
      m = mn;
    }

    #pragma unroll
    for (int r = 0; r < 4; ++r) {          // runs of 4 consecutive kv
      f16x4 h;
      #pragma unroll
      for (int j = 0; j < 4; ++j) {
        float e = __expf(S[4 * r + j] - m);   // bounded by e^8
        h[j] = (f16)e;
        l += e;                               // per-lane partial; no shfl
      }
      *(f16x4*)&Psh[qg][l31][mem * 32 + r * 8 + hi * 4] = h;
    }

    // ---- B2: P[t] visible; K[t+1] (issued ~2000 cyc ago) + V[t] drained
    asm volatile("s_waitcnt lgkmcnt(0) vmcnt(0)" ::: "memory");
    __builtin_amdgcn_s_barrier();
    __builtin_amdgcn_sched_barrier(0);
  }

  // ---- Epilogue PV[31] (trailing tile of the pipeline)
  {
    __builtin_amdgcn_s_setprio(1);
    #pragma unroll
    for (int ks = 0; ks < 4; ++ks) {
      f16x8 pf = *(const f16x8*)&Psh[qg][l31][ks * 16 + hi * 8];
      #pragma unroll
      for (int dt = 0; dt < 5; ++dt) {
        f16x8 vf = *(const f16x8*)&VTsh[dbase + dt * 32 + l31][ks * 16 + hi * 8];
        O[dt] = __builtin_amdgcn_mfma_f32_32x32x16_f16(vf, pf, O[dt], 0, 0, 0);
      }
    }
    __builtin_amdgcn_s_setprio(0);
  }

  // ---- reduce per-lane partials across hi, exchange with partner member
  l += __shfl_xor(l, 32, 64);
  if (lane < 32) MxS[qg][mem][l31] = l;
  asm volatile("s_waitcnt lgkmcnt(0)" ::: "memory");
  __builtin_amdgcn_s_barrier();
  __builtin_amdgcn_sched_barrier(0);
  float pl = MxS[qg][mem ^ 1][l31];
  float rinv = 1.0f / (l + pl);

  // ---- store: d = dbase + dt*32 + r*8 + hi*4 + j (runs align to 4; 300%4==0)
  {
    int q = qbase + l31;
    const f16* mrow = Qsrc + bq + (size_t)q * DPK;
    size_t orow = (size_t)b * (4096 * 300) + (size_t)(dir * 2048 + q) * 300;
    #pragma unroll
    for (int dt = 0; dt < 5; ++dt) {
      #pragma unroll
      for (int r = 0; r < 4; ++r) {
        int d0 = dbase + dt * 32 + r * 8 + hi * 4;
        if (d0 >= dlo && d0 < 300) {
          f16x4 mu = *(const f16x4*)(mrow + d0);
          f32x4 o;
          o[0] = O[dt][4 * r + 0] * rinv * (float)mu[0];
          o[1] = O[dt][4 * r + 1] * rinv * (float)mu[1];
          o[2] = O[dt][4 * r + 2] * rinv * (float)mu[2];
          o[3] = O[dt][4 * r + 3] * rinv * (float)mu[3];
          *(f32x4*)&out[orow + d0] = o;
        }
      }
    }
  }
}

extern "C" void kernel_launch(void* const* d_in, const int* in_sizes, int n_in,
                              void* d_out, int out_size, void* d_ws, size_t ws_size,
                              hipStream_t stream) {
  const float* X = (const float*)d_in[0];
  const float* Y = (const float*)d_in[1];
  float* out = (float*)d_out;

  size_t need = (size_t)(2 * XF_ELEMS + 2 * XT_ELEMS) * sizeof(f16);  // ~83 MB
  if (ws_size < need) return;

  // Layout: XT, YT first, Xf, Yf last — stageV's 16 B/row overread on the
  // transposed arrays lands in the following array, never past d_ws.
  f16* XT = (f16*)d_ws;
  f16* YT = XT + XT_ELEMS;
  f16* Xf = YT + XT_ELEMS;
  f16* Yf = Xf + XF_ELEMS;

  prep_kernel<<<dim3(65, 11, 32), 256, 0, stream>>>(X, Y, Xf, Yf, XT, YT);
  attn_kernel<<<dim3(512), 512, 0, stream>>>(Xf, Yf, XT, YT, out);
}